// Round 18
// baseline (98.680 us; speedup 1.0000x reference)
//
#include <hip/hip_runtime.h>

typedef short short8 __attribute__((ext_vector_type(8)));
typedef float f32x4 __attribute__((ext_vector_type(4)));
typedef unsigned short ushort_t;

__device__ inline ushort_t f2bf(float f) {
    union { float f; unsigned int u; } x{f};
    unsigned int r = (x.u + 0x7fffu + ((x.u >> 16) & 1u)) >> 16;
    return (ushort_t)r;
}

__device__ inline void gload_lds16(const void* g, void* l) {
    __builtin_amdgcn_global_load_lds(
        (const __attribute__((address_space(1))) unsigned int*)g,
        (__attribute__((address_space(3))) unsigned int*)l, 16, 0, 0);
}

template <int CTRL>
__device__ inline float dppadd(float x) {
    union { float f; int i; } u, v;
    u.f = x;
    v.i = __builtin_amdgcn_update_dpp(0, u.i, CTRL, 0xf, 0xf, true);
    return x + v.f;
}
#define DPP_XOR1 0xB1
#define DPP_XOR2 0x4E
#define DPP_HMIR 0x141
#define DPP_MIR  0x140

// ---------- kernel 0: W [1024][128] f32 -> Wt [128][1024] bf16 (x3) ----------
__global__ __launch_bounds__(1024) void wt_prep(const float* __restrict__ Wq,
                                                const float* __restrict__ Wk,
                                                const float* __restrict__ Wv,
                                                ushort_t* __restrict__ Wt) {
    __shared__ float t[32][33];
    int bz = blockIdx.z;
    const float* W = bz == 0 ? Wq : (bz == 1 ? Wk : Wv);
    int h0 = blockIdx.x * 32, c0 = blockIdx.y * 32;
    int tx = threadIdx.x, ty = threadIdx.y;
    t[ty][tx] = W[(c0 + ty) * 128 + h0 + tx];
    __syncthreads();
    Wt[bz * 131072 + (h0 + ty) * 1024 + c0 + tx] = f2bf(t[tx][ty]);
}

// ---------- kernel 1: X [16384][1024] f32 @ Wt^T -> bf16 Q/K, V (transposed) ----------
// r7-measured structure (timed ~33us, warm-stream floor). FROZEN.
__global__ __launch_bounds__(256, 4) void proj_gemm(const float* __restrict__ q,
                                                    const float* __restrict__ k,
                                                    const float* __restrict__ v,
                                                    const ushort_t* __restrict__ Wt,
                                                    ushort_t* __restrict__ Qb,
                                                    ushort_t* __restrict__ Kb,
                                                    ushort_t* __restrict__ Vt) {
    __shared__ ushort_t lA[64][72];    // 9.2 KB
    __shared__ ushort_t lB[128][72];   // 18.4 KB
    int z = blockIdx.z;
    const float* X = z == 0 ? q : (z == 1 ? k : v);
    const ushort_t* Wz = Wt + z * 131072;
    int m0 = blockIdx.x * 64;
    int tid = threadIdx.x;
    int lane = tid & 63, wv = tid >> 6;
    int g = lane >> 4, li = lane & 15;

    f32x4 z4 = {0.f, 0.f, 0.f, 0.f};
    f32x4 acc[8];
#pragma unroll
    for (int n = 0; n < 8; ++n) acc[n] = z4;

    for (int ks = 0; ks < 16; ++ks) {
        int k0 = ks * 64;
        if (ks) __syncthreads();
#pragma unroll
        for (int it = 0; it < 4; ++it) {
            int idx = it * 256 + tid;
            int row = idx >> 4, c4 = idx & 15;
            const float4 val = *(const float4*)(X + (size_t)(m0 + row) * 1024 + k0 + c4 * 4);
            ushort4 bb;
            bb.x = f2bf(val.x); bb.y = f2bf(val.y); bb.z = f2bf(val.z); bb.w = f2bf(val.w);
            *(ushort4*)&lA[row][c4 * 4] = bb;
        }
#pragma unroll
        for (int it = 0; it < 4; ++it) {
            int idx = it * 256 + tid;
            int h = idx >> 3, k8 = idx & 7;
            *(int4*)&lB[h][k8 * 8] = *(const int4*)(Wz + h * 1024 + k0 + k8 * 8);
        }
        __syncthreads();
#pragma unroll
        for (int kk = 0; kk < 2; ++kk) {
            short8 a = *(const short8*)&lA[wv * 16 + li][kk * 32 + g * 8];
            short8 b[8];
#pragma unroll
            for (int n = 0; n < 8; ++n)
                b[n] = *(const short8*)&lB[n * 16 + li][kk * 32 + g * 8];
#pragma unroll
            for (int n = 0; n < 8; ++n)
                acc[n] = __builtin_amdgcn_mfma_f32_16x16x32_bf16(a, b[n], acc[n], 0, 0, 0);
        }
    }
    if (z < 2) {
        ushort_t* Out = z == 0 ? Qb : Kb;
        int rbase = m0 + wv * 16 + g * 4;
#pragma unroll
        for (int n = 0; n < 8; ++n)
#pragma unroll
            for (int r = 0; r < 4; ++r)
                Out[(size_t)(rbase + r) * 128 + n * 16 + li] = f2bf(acc[n][r]);
    } else {
        int tbase = m0 + wv * 16 + g * 4;
#pragma unroll
        for (int n = 0; n < 8; ++n)
#pragma unroll
            for (int r = 0; r < 4; ++r) {
                int t = tbase + r;
                int bb = t >> 11, tl = t & 2047;
                Vt[((size_t)bb * 128 + n * 16 + li) * 2048 + tl] = f2bf(acc[n][r]);
            }
    }
}

// ---------- kernel 2: flash attention, causal (j <= i+1) ----------
// r15 geometry (QBLK=64, 4 waves, grid 256) + TRIPLE-buffered K/V with counted
// vmcnt (T4): per iter {vmcnt(16) -> barrier -> STAGE(jt+2) -> compute}. Tile jt's
// staging loads get TWO full iterations to complete (r15/r17's depth-1 vmcnt(0)
// exposed ~3900cy/tile of staging drain). LDS 105.2KB -> 1 block/CU.
// Hazards: STAGE(jt+2) writes buf (jt-1)%3 after the barrier where all waves
// finished reading it; vmcnt retires in issue order (m135) so vmcnt(16) drains
// exactly tile jt; gload_lds is vmcnt-only (no lgkm interaction with P fence).
__global__ __launch_bounds__(256) void attn_fwd(const ushort_t* __restrict__ Qb,
                                                const ushort_t* __restrict__ Kb,
                                                const ushort_t* __restrict__ Vt,
                                                float* __restrict__ Out) {
    constexpr float SCL = 0.08838834764831845f * 1.4426950408889634f; // 1/sqrt(128)*log2(e)
    constexpr float MB  = 8.0f * 1.4426950408889634f;                 // fixed max (scaled)
    __shared__ ushort_t Kl[3][64][128];   // 48 KB
    __shared__ ushort_t Vl[3][128][64];   // 48 KB
    __shared__ ushort_t lP[4][16][72];    // 9.2 KB

    int t = threadIdx.x;
    int lane = t & 63, wv = t >> 6;
    int g = lane >> 4, li = lane & 15;
    int b = blockIdx.x & 7;
    int qb = 31 - (blockIdx.x >> 3);      // 64-row q-blocks, longest first
    int r0 = qb * 64 + wv * 16;
    int NT = qb + 2; if (NT > 32) NT = 32;
    const ushort_t* kb0 = Kb + (size_t)b * 2048 * 128;
    const ushort_t* vb0 = Vt + (size_t)b * 128 * 2048;
    ushort_t (*P)[72] = lP[wv];

    short8 qf[4];
    const ushort_t* qrow = Qb + (size_t)(b * 2048 + r0 + li) * 128 + g * 8;
#pragma unroll
    for (int kf = 0; kf < 4; ++kf) qf[kf] = *(const short8*)(qrow + kf * 32);

    f32x4 z4 = {0.f, 0.f, 0.f, 0.f};
    f32x4 o[8];
#pragma unroll
    for (int n = 0; n < 8; ++n) o[n] = z4;
    float lr[4] = {0.f, 0.f, 0.f, 0.f};

    auto STAGE = [&](int jt, int buf) {
        int j0 = jt * 64;
        // K tile 16KB: 4 rounds x 16 rows x 256B. row r*16+(t>>4), slot t&15,
        // global chunk c = slot ^ (row&7)  (row&7 == (t>>4)&7).
#pragma unroll
        for (int r = 0; r < 4; ++r) {
            int row = r * 16 + (t >> 4);
            int c = (t & 15) ^ ((t >> 4) & 7);
            gload_lds16(kb0 + (size_t)(j0 + row) * 128 + c * 8,
                        (char*)&Kl[buf][0][0] + r * 4096 + t * 16);
        }
        // V tile 16KB: 4 rounds x 32 rows x 128B. row r*32+(t>>3), slot t&7.
#pragma unroll
        for (int r = 0; r < 4; ++r) {
            int row = r * 32 + (t >> 3);
            int c = (t & 7) ^ ((t >> 3) & 7);
            gload_lds16(vb0 + (size_t)row * 2048 + j0 + c * 8,
                        (char*)&Vl[buf][0][0] + r * 4096 + t * 16);
        }
    };

    STAGE(0, 0);
    if (NT > 1) STAGE(1, 1);

    for (int jt = 0; jt < NT; ++jt) {
        int buf = jt - (jt / 3) * 3;      // jt % 3
        int j0 = jt * 64;
        // drain tile jt's 16 loads; tile jt+1's 16 may stay in flight
        if (jt + 1 < NT) {
            asm volatile("s_waitcnt vmcnt(16)" ::: "memory");
        } else {
            asm volatile("s_waitcnt vmcnt(0)" ::: "memory");
        }
        __builtin_amdgcn_sched_barrier(0);
        __builtin_amdgcn_s_barrier();     // all waves: buf ready, prev reads done
        if (jt + 2 < NT) STAGE(jt + 2, (jt + 2) - ((jt + 2) / 3) * 3);

        const char* kb = (const char*)&Kl[buf][0][0];
        const char* vb = (const char*)&Vl[buf][0][0];

        f32x4 s[4];
#pragma unroll
        for (int jf = 0; jf < 4; ++jf) s[jf] = z4;
#pragma unroll
        for (int jf = 0; jf < 4; ++jf)
#pragma unroll
            for (int kf = 0; kf < 4; ++kf) {
                short8 kfrag = *(const short8*)(kb + (jf * 16 + li) * 256 +
                                                (((kf * 4 + g) ^ (li & 7)) * 16));
                s[jf] = __builtin_amdgcn_mfma_f32_16x16x32_bf16(qf[kf], kfrag, s[jf], 0, 0, 0);
            }
        if (j0 + 63 > r0 + 1) {
#pragma unroll
            for (int jf = 0; jf < 4; ++jf)
#pragma unroll
                for (int r = 0; r < 4; ++r) {
                    int j = j0 + jf * 16 + li;
                    int i = r0 + g * 4 + r;
                    if (j > i + 1) s[jf][r] = -1e30f;
                }
        }
#pragma unroll
        for (int jf = 0; jf < 4; ++jf)
#pragma unroll
            for (int r = 0; r < 4; ++r) {
                float p = exp2f(s[jf][r] * SCL - MB);
                lr[r] += p;
                P[g * 4 + r][jf * 16 + li] = f2bf(p);
            }
        // wave-internal RAW through LDS P (rule 18: drain + fence)
        asm volatile("s_waitcnt lgkmcnt(0)" ::: "memory");
        __builtin_amdgcn_sched_barrier(0);
        short8 pa0 = *(const short8*)&P[li][g * 8];
        short8 pa1 = *(const short8*)&P[li][32 + g * 8];
#pragma unroll
        for (int n = 0; n < 8; ++n) {
            short8 vf = *(const short8*)(vb + (n * 16 + li) * 128 +
                                         ((g ^ (li & 7)) * 16));
            o[n] = __builtin_amdgcn_mfma_f32_16x16x32_bf16(pa0, vf, o[n], 0, 0, 0);
        }
#pragma unroll
        for (int n = 0; n < 8; ++n) {
            short8 vf = *(const short8*)(vb + (n * 16 + li) * 128 +
                                         (((4 + g) ^ (li & 7)) * 16));
            o[n] = __builtin_amdgcn_mfma_f32_16x16x32_bf16(pa1, vf, o[n], 0, 0, 0);
        }
        // no end-of-iter drain: next iter's counted vmcnt handles pacing
    }

#pragma unroll
    for (int r = 0; r < 4; ++r) {
        lr[r] = dppadd<DPP_XOR1>(lr[r]);
        lr[r] = dppadd<DPP_XOR2>(lr[r]);
        lr[r] = dppadd<DPP_HMIR>(lr[r]);
        lr[r] = dppadd<DPP_MIR>(lr[r]);
    }
#pragma unroll
    for (int r = 0; r < 4; ++r) {
        float inv = 1.0f / lr[r];
        int i = r0 + g * 4 + r;
        float* op = Out + (size_t)(b * 2048 + i) * 128 + li;
#pragma unroll
        for (int n = 0; n < 8; ++n)
            op[n * 16] = o[n][r] * inv;
    }
}

extern "C" void kernel_launch(void* const* d_in, const int* in_sizes, int n_in,
                              void* d_out, int out_size, void* d_ws, size_t ws_size,
                              hipStream_t stream) {
    const float* q  = (const float*)d_in[0];
    const float* k  = (const float*)d_in[1];
    const float* v  = (const float*)d_in[2];
    const float* Wq = (const float*)d_in[3];
    const float* Wk = (const float*)d_in[4];
    const float* Wv = (const float*)d_in[5];
    float* Out = (float*)d_out;

    ushort_t* Qb = (ushort_t*)d_ws;          // [16384][128] bf16
    ushort_t* Kb = Qb + 2097152;             // [16384][128] bf16
    ushort_t* Vt = Kb + 2097152;             // [8][128][2048] bf16
    ushort_t* Wt = Vt + 2097152;             // [3][128][1024] bf16

    wt_prep<<<dim3(4, 32, 3), dim3(32, 32), 0, stream>>>(Wq, Wk, Wv, Wt);
    proj_gemm<<<dim3(256, 1, 3), 256, 0, stream>>>(q, k, v, Wt, Qb, Kb, Vt);
    attn_fwd<<<dim3(256), 256, 0, stream>>>(Qb, Kb, Vt, Out);
}

// Round 20
// 79.258 us; speedup vs baseline: 1.2450x; 1.2450x over previous
//
#include <hip/hip_runtime.h>

typedef short short8 __attribute__((ext_vector_type(8)));
typedef float f32x4 __attribute__((ext_vector_type(4)));
typedef unsigned short ushort_t;

__device__ inline ushort_t f2bf(float f) {
    union { float f; unsigned int u; } x{f};
    unsigned int r = (x.u + 0x7fffu + ((x.u >> 16) & 1u)) >> 16;
    return (ushort_t)r;
}
__device__ inline float bf2f(ushort_t u) {
    union { unsigned int u; float f; } x{(unsigned int)u << 16};
    return x.f;
}

__device__ inline void gload_lds16(const void* g, void* l) {
    __builtin_amdgcn_global_load_lds(
        (const __attribute__((address_space(1))) unsigned int*)g,
        (__attribute__((address_space(3))) unsigned int*)l, 16, 0, 0);
}

template <int CTRL>
__device__ inline float dppadd(float x) {
    union { float f; int i; } u, v;
    u.f = x;
    v.i = __builtin_amdgcn_update_dpp(0, u.i, CTRL, 0xf, 0xf, true);
    return x + v.f;
}
#define DPP_XOR1 0xB1
#define DPP_XOR2 0x4E
#define DPP_HMIR 0x141
#define DPP_MIR  0x140

// ---------- kernel 0: W [1024][128] f32 -> Wt [128][1024] bf16 (x3) ----------
__global__ __launch_bounds__(1024) void wt_prep(const float* __restrict__ Wq,
                                                const float* __restrict__ Wk,
                                                const float* __restrict__ Wv,
                                                ushort_t* __restrict__ Wt) {
    __shared__ float t[32][33];
    int bz = blockIdx.z;
    const float* W = bz == 0 ? Wq : (bz == 1 ? Wk : Wv);
    int h0 = blockIdx.x * 32, c0 = blockIdx.y * 32;
    int tx = threadIdx.x, ty = threadIdx.y;
    t[ty][tx] = W[(c0 + ty) * 128 + h0 + tx];
    __syncthreads();
    Wt[bz * 131072 + (h0 + ty) * 1024 + c0 + tx] = f2bf(t[tx][ty]);
}

// ---------- kernel 1: X [16384][1024] f32 @ Wt^T -> bf16 Q/K, V (transposed) ----------
// r7-measured structure (timed ~33us, warm-stream floor). FROZEN.
__global__ __launch_bounds__(256, 4) void proj_gemm(const float* __restrict__ q,
                                                    const float* __restrict__ k,
                                                    const float* __restrict__ v,
                                                    const ushort_t* __restrict__ Wt,
                                                    ushort_t* __restrict__ Qb,
                                                    ushort_t* __restrict__ Kb,
                                                    ushort_t* __restrict__ Vt) {
    __shared__ ushort_t lA[64][72];    // 9.2 KB
    __shared__ ushort_t lB[128][72];   // 18.4 KB
    int z = blockIdx.z;
    const float* X = z == 0 ? q : (z == 1 ? k : v);
    const ushort_t* Wz = Wt + z * 131072;
    int m0 = blockIdx.x * 64;
    int tid = threadIdx.x;
    int lane = tid & 63, wv = tid >> 6;
    int g = lane >> 4, li = lane & 15;

    f32x4 z4 = {0.f, 0.f, 0.f, 0.f};
    f32x4 acc[8];
#pragma unroll
    for (int n = 0; n < 8; ++n) acc[n] = z4;

    for (int ks = 0; ks < 16; ++ks) {
        int k0 = ks * 64;
        if (ks) __syncthreads();
#pragma unroll
        for (int it = 0; it < 4; ++it) {
            int idx = it * 256 + tid;
            int row = idx >> 4, c4 = idx & 15;
            const float4 val = *(const float4*)(X + (size_t)(m0 + row) * 1024 + k0 + c4 * 4);
            ushort4 bb;
            bb.x = f2bf(val.x); bb.y = f2bf(val.y); bb.z = f2bf(val.z); bb.w = f2bf(val.w);
            *(ushort4*)&lA[row][c4 * 4] = bb;
        }
#pragma unroll
        for (int it = 0; it < 4; ++it) {
            int idx = it * 256 + tid;
            int h = idx >> 3, k8 = idx & 7;
            *(int4*)&lB[h][k8 * 8] = *(const int4*)(Wz + h * 1024 + k0 + k8 * 8);
        }
        __syncthreads();
#pragma unroll
        for (int kk = 0; kk < 2; ++kk) {
            short8 a = *(const short8*)&lA[wv * 16 + li][kk * 32 + g * 8];
            short8 b[8];
#pragma unroll
            for (int n = 0; n < 8; ++n)
                b[n] = *(const short8*)&lB[n * 16 + li][kk * 32 + g * 8];
#pragma unroll
            for (int n = 0; n < 8; ++n)
                acc[n] = __builtin_amdgcn_mfma_f32_16x16x32_bf16(a, b[n], acc[n], 0, 0, 0);
        }
    }
    if (z < 2) {
        ushort_t* Out = z == 0 ? Qb : Kb;
        int rbase = m0 + wv * 16 + g * 4;
#pragma unroll
        for (int n = 0; n < 8; ++n)
#pragma unroll
            for (int r = 0; r < 4; ++r)
                Out[(size_t)(rbase + r) * 128 + n * 16 + li] = f2bf(acc[n][r]);
    } else {
        int tbase = m0 + wv * 16 + g * 4;
#pragma unroll
        for (int n = 0; n < 8; ++n)
#pragma unroll
            for (int r = 0; r < 4; ++r) {
                int t = tbase + r;
                int bb = t >> 11, tl = t & 2047;
                Vt[((size_t)bb * 128 + n * 16 + li) * 2048 + tl] = f2bf(acc[n][r]);
            }
    }
}

// ---------- kernel 2: flash attention pass 1, causal (j <= i+1), SPLIT-KV x2 ----------
// r15 tile structure (QBLK=64, 4 waves, double-buffered gload_lds K/V, XOR swizzle,
// fixed-max softmax). NEW: each q-block's KV range is split across 2 blocks
// (s=0: jt<[h0], s=1: jt>=h0) -> critical path 32 -> ~16 tiles; grid 512 = exactly
// 2 blocks/CU. Fixed-max makes partials PLAIN SUMS: block writes o-partial (bf16)
// + l-partial (f32) to ws; combine kernel divides. s=0 always holds j<=1 -> L>0.
__global__ __launch_bounds__(256) void attn_fwd(const ushort_t* __restrict__ Qb,
                                                const ushort_t* __restrict__ Kb,
                                                const ushort_t* __restrict__ Vt,
                                                ushort_t* __restrict__ oPb,
                                                float* __restrict__ lPf) {
    constexpr float SCL = 0.08838834764831845f * 1.4426950408889634f; // 1/sqrt(128)*log2(e)
    constexpr float MB  = 8.0f * 1.4426950408889634f;                 // fixed max (scaled)
    __shared__ ushort_t Kl[2][64][128];   // 32 KB
    __shared__ ushort_t Vl[2][128][64];   // 32 KB
    __shared__ ushort_t lP[4][16][72];    // 9.2 KB   (total 73.2 KB -> 2 blocks/CU)

    int t = threadIdx.x;
    int lane = t & 63, wv = t >> 6;
    int g = lane >> 4, li = lane & 15;
    int b = blockIdx.x & 7;
    int idx = blockIdx.x >> 3;            // 0..63
    int qb = 31 - (idx >> 1);             // longest first
    int s  = idx & 1;                     // KV-half
    int r0 = qb * 64 + wv * 16;
    int NT = qb + 2; if (NT > 32) NT = 32;
    int h0 = (NT + 1) >> 1;
    int jb = s ? h0 : 0;
    int je = s ? NT : h0;
    const ushort_t* kb0 = Kb + (size_t)b * 2048 * 128;
    const ushort_t* vb0 = Vt + (size_t)b * 128 * 2048;
    ushort_t (*P)[72] = lP[wv];

    short8 qf[4];
    const ushort_t* qrow = Qb + (size_t)(b * 2048 + r0 + li) * 128 + g * 8;
#pragma unroll
    for (int kf = 0; kf < 4; ++kf) qf[kf] = *(const short8*)(qrow + kf * 32);

    f32x4 z4 = {0.f, 0.f, 0.f, 0.f};
    f32x4 o[8];
#pragma unroll
    for (int n = 0; n < 8; ++n) o[n] = z4;
    float lr[4] = {0.f, 0.f, 0.f, 0.f};

    auto STAGE = [&](int jt, int buf) {
        int j0 = jt * 64;
#pragma unroll
        for (int r = 0; r < 4; ++r) {
            int row = r * 16 + (t >> 4);
            int c = (t & 15) ^ ((t >> 4) & 7);
            gload_lds16(kb0 + (size_t)(j0 + row) * 128 + c * 8,
                        (char*)&Kl[buf][0][0] + r * 4096 + t * 16);
        }
#pragma unroll
        for (int r = 0; r < 4; ++r) {
            int row = r * 32 + (t >> 3);
            int c = (t & 7) ^ ((t >> 3) & 7);
            gload_lds16(vb0 + (size_t)row * 2048 + j0 + c * 8,
                        (char*)&Vl[buf][0][0] + r * 4096 + t * 16);
        }
    };

    STAGE(jb, 0);
    asm volatile("s_waitcnt vmcnt(0)" ::: "memory");
    __builtin_amdgcn_s_barrier();

    for (int jt = jb; jt < je; ++jt) {
        int buf = (jt - jb) & 1;
        int j0 = jt * 64;
        if (jt + 1 < je) STAGE(jt + 1, buf ^ 1);
        const char* kb = (const char*)&Kl[buf][0][0];
        const char* vb = (const char*)&Vl[buf][0][0];

        f32x4 sA[4];
#pragma unroll
        for (int jf = 0; jf < 4; ++jf) sA[jf] = z4;
#pragma unroll
        for (int jf = 0; jf < 4; ++jf)
#pragma unroll
            for (int kf = 0; kf < 4; ++kf) {
                short8 kfrag = *(const short8*)(kb + (jf * 16 + li) * 256 +
                                                (((kf * 4 + g) ^ (li & 7)) * 16));
                sA[jf] = __builtin_amdgcn_mfma_f32_16x16x32_bf16(qf[kf], kfrag, sA[jf], 0, 0, 0);
            }
        if (j0 + 63 > r0 + 1) {
#pragma unroll
            for (int jf = 0; jf < 4; ++jf)
#pragma unroll
                for (int r = 0; r < 4; ++r) {
                    int j = j0 + jf * 16 + li;
                    int i = r0 + g * 4 + r;
                    if (j > i + 1) sA[jf][r] = -1e30f;
                }
        }
#pragma unroll
        for (int jf = 0; jf < 4; ++jf)
#pragma unroll
            for (int r = 0; r < 4; ++r) {
                float p = exp2f(sA[jf][r] * SCL - MB);
                lr[r] += p;
                P[g * 4 + r][jf * 16 + li] = f2bf(p);
            }
        // wave-internal RAW through LDS P (rule 18: drain + fence)
        asm volatile("s_waitcnt lgkmcnt(0)" ::: "memory");
        __builtin_amdgcn_sched_barrier(0);
        short8 pa0 = *(const short8*)&P[li][g * 8];
        short8 pa1 = *(const short8*)&P[li][32 + g * 8];
#pragma unroll
        for (int n = 0; n < 8; ++n) {
            short8 vf = *(const short8*)(vb + (n * 16 + li) * 128 +
                                         ((g ^ (li & 7)) * 16));
            o[n] = __builtin_amdgcn_mfma_f32_16x16x32_bf16(pa0, vf, o[n], 0, 0, 0);
        }
#pragma unroll
        for (int n = 0; n < 8; ++n) {
            short8 vf = *(const short8*)(vb + (n * 16 + li) * 128 +
                                         (((4 + g) ^ (li & 7)) * 16));
            o[n] = __builtin_amdgcn_mfma_f32_16x16x32_bf16(pa1, vf, o[n], 0, 0, 0);
        }
        asm volatile("s_waitcnt vmcnt(0)" ::: "memory");
        __builtin_amdgcn_s_barrier();
    }

#pragma unroll
    for (int r = 0; r < 4; ++r) {
        lr[r] = dppadd<DPP_XOR1>(lr[r]);
        lr[r] = dppadd<DPP_XOR2>(lr[r]);
        lr[r] = dppadd<DPP_HMIR>(lr[r]);
        lr[r] = dppadd<DPP_MIR>(lr[r]);
    }
    // partial epilogue: bf16 o-partials + f32 l-partials (no divide)
    if (li == 0) {
#pragma unroll
        for (int r = 0; r < 4; ++r)
            lPf[s * 16384 + b * 2048 + r0 + g * 4 + r] = lr[r];
    }
#pragma unroll
    for (int r = 0; r < 4; ++r) {
        size_t base = ((size_t)s * 16384 + b * 2048 + r0 + g * 4 + r) * 128 + li;
#pragma unroll
        for (int n = 0; n < 8; ++n)
            oPb[base + n * 16] = f2bf(o[n][r]);
    }
}

// ---------- kernel 3: combine: out = (o0+o1)/(l0+l1) ----------
__global__ __launch_bounds__(256) void attn_combine(const ushort_t* __restrict__ oPb,
                                                    const float* __restrict__ lPf,
                                                    float* __restrict__ Out) {
    int gid = blockIdx.x * 256 + threadIdx.x;   // 256K threads x 8 elems
    int row = gid >> 4;                          // 16 chunks of 8 per row
    int c8 = (gid & 15) * 8;
    float inv = 1.0f / (lPf[row] + lPf[16384 + row]);
    const ushort_t* p0 = oPb + (size_t)row * 128 + c8;
    const ushort_t* p1 = p0 + (size_t)16384 * 128;
    short8 a = *(const short8*)p0;
    short8 bb = *(const short8*)p1;
    float* op = Out + (size_t)row * 128 + c8;
    float4 r0v, r1v;
    float* rp0 = (float*)&r0v;
    float* rp1 = (float*)&r1v;
#pragma unroll
    for (int j = 0; j < 4; ++j)
        rp0[j] = (bf2f((ushort_t)a[j]) + bf2f((ushort_t)bb[j])) * inv;
#pragma unroll
    for (int j = 0; j < 4; ++j)
        rp1[j] = (bf2f((ushort_t)a[4 + j]) + bf2f((ushort_t)bb[4 + j])) * inv;
    *(float4*)op = r0v;
    *(float4*)(op + 4) = r1v;
}

extern "C" void kernel_launch(void* const* d_in, const int* in_sizes, int n_in,
                              void* d_out, int out_size, void* d_ws, size_t ws_size,
                              hipStream_t stream) {
    const float* q  = (const float*)d_in[0];
    const float* k  = (const float*)d_in[1];
    const float* v  = (const float*)d_in[2];
    const float* Wq = (const float*)d_in[3];
    const float* Wk = (const float*)d_in[4];
    const float* Wv = (const float*)d_in[5];
    float* Out = (float*)d_out;

    ushort_t* Qb  = (ushort_t*)d_ws;         // [16384][128] bf16       4 MB
    ushort_t* Kb  = Qb + 2097152;            // [16384][128] bf16       4 MB
    ushort_t* Vt  = Kb + 2097152;            // [8][128][2048] bf16     4 MB
    ushort_t* Wt  = Vt + 2097152;            // [3][128][1024] bf16   0.75 MB
    ushort_t* oPb = Wt + 393216;             // [2][16384][128] bf16    8 MB
    float*    lPf = (float*)(oPb + 4194304); // [2][16384] f32       0.13 MB   total ~20.9 MB

    wt_prep<<<dim3(4, 32, 3), dim3(32, 32), 0, stream>>>(Wq, Wk, Wv, Wt);
    proj_gemm<<<dim3(256, 1, 3), 256, 0, stream>>>(q, k, v, Wt, Qb, Kb, Vt);
    attn_fwd<<<dim3(512), 256, 0, stream>>>(Qb, Kb, Vt, oPb, lPf);
    attn_combine<<<dim3(1024), 256, 0, stream>>>(oPb, lPf, Out);
}